// Round 1
// baseline (12597.552 us; speedup 1.0000x reference)
//
#include <hip/hip_runtime.h>
#include <hip/hip_bf16.h>
#include <stdint.h>

// Problem constants (fixed by the reference): B=64, L=4, H=1024, T=128.
#define NB   64
#define NH   1024
#define NL   4
#define NT   128

using bf16x8 = __attribute__((ext_vector_type(8))) short;  // 8 bf16 in 4 VGPRs
using f32x4  = __attribute__((ext_vector_type(4))) float;

// Split fp32 v into hi+lo bf16 (RNE). v ~= hi + lo with residual ~2^-17 * |v|.
__device__ __forceinline__ void split_bf16(float v, unsigned short& hi, unsigned short& lo) {
    unsigned u = __float_as_uint(v);
    unsigned short h = (unsigned short)((u + 0x7FFFu + ((u >> 16) & 1u)) >> 16);
    float hf = __uint_as_float((unsigned)h << 16);
    float r  = v - hf;
    unsigned ur = __float_as_uint(r);
    unsigned short l = (unsigned short)((ur + 0x7FFFu + ((ur >> 16) & 1u)) >> 16);
    hi = h; lo = l;
}

// ---------------------------------------------------------------------------
// prep_w: fp32 W_ih/W_hh -> swizzled hi/lo bf16 B-fragment tiles.
// Virtual gate-row order n' = j*4 + g (g in [i,f,g,o]) so block bj owns rows
// n' in [bj*16, bj*16+16) = 4 h-dims x 4 gates.
// Tile layout: [l][kc(64)][nt(256)][lane(64)][8] bf16; lane L holds
// B[k=kc*32+(L>>4)*8+j][n'=nt*16+(L&15)] = W[n][k].
// ---------------------------------------------------------------------------
__global__ __launch_bounds__(256)
void prep_w(const float* __restrict__ Wih, const float* __restrict__ Whh,
            unsigned short* __restrict__ Whi, unsigned short* __restrict__ Wlo)
{
    int gid = blockIdx.x * 256 + threadIdx.x;      // (l, kc, nt, L)
    int L  = gid & 63;
    int nt = (gid >> 6) & 255;
    int kc = (gid >> 14) & 63;
    int l  = gid >> 20;                            // 0..3
    int np = nt * 16 + (L & 15);                   // n' in [0,4096)
    int g  = np & 3, j = np >> 2;
    int n  = g * 1024 + j;                         // original gate row
    int k0 = kc * 32 + (L >> 4) * 8;               // k in [0,2048)
    const float* src = (k0 < 1024)
        ? (Wih + ((size_t)l * 4096 + n) * 1024 + k0)
        : (Whh + ((size_t)l * 4096 + n) * 1024 + (k0 - 1024));
    float4 s0 = *(const float4*)(src);
    float4 s1 = *(const float4*)(src + 4);
    float sv[8] = {s0.x, s0.y, s0.z, s0.w, s1.x, s1.y, s1.z, s1.w};
    unsigned short hb[8], lb[8];
#pragma unroll
    for (int e = 0; e < 8; ++e) split_bf16(sv[e], hb[e], lb[e]);
    size_t dst = (((size_t)l * 64 + kc) * 256 + nt) * 512 + (size_t)L * 8;
    *(ushort4*)&Whi[dst]     = make_ushort4(hb[0], hb[1], hb[2], hb[3]);
    *(ushort4*)&Whi[dst + 4] = make_ushort4(hb[4], hb[5], hb[6], hb[7]);
    *(ushort4*)&Wlo[dst]     = make_ushort4(lb[0], lb[1], lb[2], lb[3]);
    *(ushort4*)&Wlo[dst + 4] = make_ushort4(lb[4], lb[5], lb[6], lb[7]);
}

// ---------------------------------------------------------------------------
// prep_state: x -> Xhi/Xlo (A-swizzle), h0 -> H(parity0) hi/lo (A-swizzle).
// A-swizzle for a (64 x 1024) activation: element (m,k) at
// ((k>>5)*4 + (m>>4))*512 + ((m&15) + ((k>>3)&3)*16)*8 + (k&7).
// ---------------------------------------------------------------------------
__device__ __forceinline__ size_t aswz(int m, int k) {
    return ((size_t)((k >> 5) * 4 + (m >> 4)) * 64 + ((m & 15) + ((k >> 3) & 3) * 16)) * 8
           + (k & 7);
}

__global__ __launch_bounds__(256)
void prep_state(const float* __restrict__ x, const float* __restrict__ h0,
                unsigned short* __restrict__ Xhi, unsigned short* __restrict__ Xlo,
                unsigned short* __restrict__ Hhi, unsigned short* __restrict__ Hlo)
{
    int gid = blockIdx.x * 256 + threadIdx.x;
    if (gid >= 5 * 65536) return;
    int buf = gid >> 16;             // 0 = x, 1..4 = layer buf-1
    int e = gid & 65535;
    int b = e >> 10, jg = e & 1023;
    float v = (buf == 0) ? x[e] : h0[(size_t)(buf - 1) * 65536 + e];
    size_t idx = aswz(b, jg);
    unsigned short hh, hl; split_bf16(v, hh, hl);
    if (buf == 0) { Xhi[idx] = hh; Xlo[idx] = hl; }
    else {
        Hhi[(size_t)(buf - 1) * 65536 + idx] = hh;
        Hlo[(size_t)(buf - 1) * 65536 + idx] = hl;
    }
}

// ---------------------------------------------------------------------------
// cell_kernel: one (t, l) LSTM cell. grid=256 blocks (N'=16 each), 768 thr =
// 12 waves = 4 M-quarters x 3 split segments (s0: hi*hi, s1: lo*hi, s2: hi*lo).
// B tiles double-buffered in LDS; barrier = raw lgkmcnt(0)+s_barrier so
// global prefetches (vmcnt) stay in flight across iterations.
// ---------------------------------------------------------------------------
#define CELL_BAR() asm volatile("s_waitcnt lgkmcnt(0)\n\ts_barrier" ::: "memory")

__global__ __launch_bounds__(768)
void cell_kernel(const unsigned short* __restrict__ AhiI, const unsigned short* __restrict__ AloI,
                 const unsigned short* __restrict__ AhiR, const unsigned short* __restrict__ AloR,
                 const unsigned short* __restrict__ Whi, const unsigned short* __restrict__ Wlo,
                 const float* __restrict__ bih, const float* __restrict__ bhh,
                 float* __restrict__ c,
                 unsigned short* __restrict__ Hhi, unsigned short* __restrict__ Hlo,
                 float* __restrict__ outp, int t)
{
    __shared__ unsigned short Bs[2][2][512];   // [buf][part hi/lo][1KB tile]
    __shared__ float Gs[12 * 256];             // segment partial gates

    const int tid = threadIdx.x;
    const int L = tid & 63;
    const int w = tid >> 6;          // 0..11
    const int q = w & 3;             // M-quarter
    const int s = w >> 2;            // split segment 0..2
    const int bj = blockIdx.x;       // n'-tile

    const bool stager = (tid < 256);
    const unsigned short* wstage = (tid & 128) ? Wlo : Whi;
    const int spart = (tid >> 7) & 1;
    const int idx8 = tid & 127;

    const unsigned short* AIs = (s == 1) ? AloI : AhiI;   // k < 1024: layer input
    const unsigned short* ARs = (s == 1) ? AloR : AhiR;   // k >= 1024: recurrent h
    const int bpart = (s == 2) ? 1 : 0;

    f32x4 acc = {0.f, 0.f, 0.f, 0.f};
    const size_t alane = ((size_t)q * 64 + L) * 8;

    // prologue: stage B(0), prefetch A(0)
    ushort4 breg;
    if (stager) {
        breg = *(const ushort4*)(wstage + (size_t)bj * 512 + idx8 * 4);
        *(ushort4*)&Bs[0][spart][idx8 * 4] = breg;
    }
    bf16x8 a_next = *(const bf16x8*)(AIs + alane);
    CELL_BAR();

    for (int kc = 0; kc < 64; ++kc) {
        const int cur = kc & 1;
        if (stager && kc < 63)
            breg = *(const ushort4*)(wstage + ((size_t)((kc + 1) * 256 + bj)) * 512 + idx8 * 4);
        bf16x8 a_cur = a_next;
        if (kc < 63) {
            const int kn = kc + 1;
            const unsigned short* Asrc = (kn < 32) ? AIs : ARs;
            const int kcl = kn & 31;
            a_next = *(const bf16x8*)(Asrc + (size_t)kcl * 2048 + alane);
        }
        bf16x8 bfrag = *(const bf16x8*)(&Bs[cur][bpart][L * 8]);
        acc = __builtin_amdgcn_mfma_f32_16x16x32_bf16(a_cur, bfrag, acc, 0, 0, 0);
        if (stager && kc < 63)
            *(ushort4*)&Bs[cur ^ 1][spart][idx8 * 4] = breg;
        CELL_BAR();
    }

    // scatter segment accumulators: lane holds D[m=(L>>4)*4+r][n'=L&15]
    {
        float* gw = &Gs[(s * 4 + q) * 256];
        const int nl = L & 15, mq = L >> 4;
#pragma unroll
        for (int r = 0; r < 4; ++r) gw[(mq * 4 + r) * 16 + nl] = acc[r];
    }
    __syncthreads();

    if (tid < 256) {
        const int bl = tid & 63;          // batch
        const int jl = tid >> 6;          // local j 0..3
        const int qq = bl >> 4, ml = bl & 15;
        const int base = qq * 256 + ml * 16 + jl * 4;
        float4 g0 = *(const float4*)(&Gs[0 * 1024 + base]);
        float4 g1 = *(const float4*)(&Gs[1 * 1024 + base]);
        float4 g2 = *(const float4*)(&Gs[2 * 1024 + base]);
        const int jg = bj * 4 + jl;
        float gi = g0.x + g1.x + g2.x + bih[jg]        + bhh[jg];
        float gf = g0.y + g1.y + g2.y + bih[1024 + jg] + bhh[1024 + jg];
        float gg = g0.z + g1.z + g2.z + bih[2048 + jg] + bhh[2048 + jg];
        float go = g0.w + g1.w + g2.w + bih[3072 + jg] + bhh[3072 + jg];

        float si = 1.f / (1.f + __expf(-gi));
        float sf = 1.f / (1.f + __expf(-gf));
        float so = 1.f / (1.f + __expf(-go));
        float tg = 1.f - 2.f / (__expf(2.f * gg) + 1.f);
        float cold = c[bl * 1024 + jg];
        float cn = sf * cold + si * tg;
        c[bl * 1024 + jg] = cn;
        float tc = 1.f - 2.f / (__expf(2.f * cn) + 1.f);
        float hv = so * tc;

        unsigned short hh, hl; split_bf16(hv, hh, hl);
        size_t hidx = aswz(bl, jg);
        Hhi[hidx] = hh; Hlo[hidx] = hl;
        if (outp) outp[(size_t)bl * (NT * NH) + (size_t)t * NH + jg] = hv;
    }
}

// ---------------------------------------------------------------------------
extern "C" void kernel_launch(void* const* d_in, const int* in_sizes, int n_in,
                              void* d_out, int out_size, void* d_ws, size_t ws_size,
                              hipStream_t stream)
{
    const float* x   = (const float*)d_in[0];
    const float* h0  = (const float*)d_in[1];
    const float* c0  = (const float*)d_in[2];
    const float* Wih = (const float*)d_in[3];
    const float* Whh = (const float*)d_in[4];
    const float* bih = (const float*)d_in[5];
    const float* bhh = (const float*)d_in[6];
    float* out = (float*)d_out;

    char* ws = (char*)d_ws;
    size_t off = 0;
    auto alloc = [&](size_t bytes) -> char* {
        char* p = ws + off; off += (bytes + 255) & ~(size_t)255; return p;
    };
    // weights: 4 layers * 64 kc * 256 nt * 512 ushorts
    unsigned short* Whi = (unsigned short*)alloc((size_t)4 * 64 * 256 * 512 * 2);
    unsigned short* Wlo = (unsigned short*)alloc((size_t)4 * 64 * 256 * 512 * 2);
    unsigned short* Xhi = (unsigned short*)alloc(65536 * 2);
    unsigned short* Xlo = (unsigned short*)alloc(65536 * 2);
    // H state: [parity 2][layer 4][65536]
    unsigned short* Hhi = (unsigned short*)alloc((size_t)2 * 4 * 65536 * 2);
    unsigned short* Hlo = (unsigned short*)alloc((size_t)2 * 4 * 65536 * 2);
    float* c = (float*)alloc((size_t)4 * 65536 * 4);

    hipMemcpyAsync(c, c0, (size_t)4 * 65536 * 4, hipMemcpyDeviceToDevice, stream);
    prep_w<<<16384, 256, 0, stream>>>(Wih, Whh, Whi, Wlo);
    prep_state<<<(5 * 65536 + 255) / 256, 256, 0, stream>>>(x, h0, Xhi, Xlo, Hhi, Hlo);

    auto H = [&](int p, int l) -> size_t { return ((size_t)p * 4 + l) * 65536; };

    for (int t = 0; t < NT; ++t) {
        const int pr = t & 1;          // parity read (recurrent, and layer-0 input)
        const int pw = (t + 1) & 1;    // parity write (and layer>0 input this step)
        for (int l = 0; l < NL; ++l) {
            const unsigned short *ahiI, *aloI;
            if (l == 0) {
                if (t == 0) { ahiI = Xhi; aloI = Xlo; }
                else        { ahiI = Hhi + H(pr, 3); aloI = Hlo + H(pr, 3); }
            } else          { ahiI = Hhi + H(pw, l - 1); aloI = Hlo + H(pw, l - 1); }
            cell_kernel<<<256, 768, 0, stream>>>(
                ahiI, aloI,
                Hhi + H(pr, l), Hlo + H(pr, l),
                Whi + (size_t)l * 8388608, Wlo + (size_t)l * 8388608,
                bih + l * 4096, bhh + l * 4096,
                c + (size_t)l * 65536,
                Hhi + H(pw, l), Hlo + H(pw, l),
                (l == 3) ? out : (float*)nullptr, t);
        }
    }
    (void)in_sizes; (void)n_in; (void)out_size; (void)ws_size;
}